// Round 7
// baseline (361.435 us; speedup 1.0000x reference)
//
#include <hip/hip_runtime.h>
#include <math.h>

#define BB 256
#define VV 4096
#define DD 64

typedef __attribute__((ext_vector_type(8))) _Float16 f16x8;
typedef __attribute__((ext_vector_type(4))) float f32x4;

// ---------------------------------------------------------------------------
// Kernel 1: one block (512 threads, 8 waves) per a. Wave w owns v-rows
// [512w, 512w+512) x ALL 256 b-cols (no duplicated F reads — r5 lesson).
// lan fragments fp16 in regs (128 VGPR), read DIRECTLY from global (lan is
// 64 KB, L2/L3-resident; kills the r6 LDS bank-conflict prologue).
// F loaded in A-fragment order with a 3-deep STATICALLY-NAMED prefetch
// pipeline (rule #20). __launch_bounds__(512,1): this toolchain treats arg2
// as min-blocks/CU (r6 evidence: (512,2) -> 128-VGPR cap -> spill disaster);
// 1 block/CU -> 256-VGPR cap, ~230 demanded, no spill.
// No LDS / barriers in main loop. Output transposed: max0T[a*256+b].
// ---------------------------------------------------------------------------
__global__ __launch_bounds__(512, 1) void topk_sim_kernel(
    const float* __restrict__ F, const float* __restrict__ lan,
    float* __restrict__ max0T, float* __restrict__ max1T)
{
  __shared__ float mrg[8][BB][2];                // 16 KB cross-wave merge
  const int t = threadIdx.x;
  const int a = blockIdx.x;
  const int wave = t >> 6;
  const int lane = t & 63;
  const int cl = lane & 15;      // A-row / B-col within 16x16 tile
  const int o  = lane >> 4;      // k-octet group

  // ---- B fragments for all 16 column-tiles, fp16, direct from global ----
  f16x8 bf[16][2];
#pragma unroll
  for (int ct = 0; ct < 16; ++ct)
#pragma unroll
    for (int s = 0; s < 2; ++s) {
      const float4* p = (const float4*)(lan + (ct * 16 + cl) * DD + s * 32 + o * 8);
      float4 u0 = p[0], u1 = p[1];
      f16x8 v;
      v[0] = (_Float16)u0.x; v[1] = (_Float16)u0.y;
      v[2] = (_Float16)u0.z; v[3] = (_Float16)u0.w;
      v[4] = (_Float16)u1.x; v[5] = (_Float16)u1.y;
      v[6] = (_Float16)u1.z; v[7] = (_Float16)u1.w;
      bf[ct][s] = v;
    }

  float m0[16], m1[16];
#pragma unroll
  for (int ct = 0; ct < 16; ++ct) { m0[ct] = -INFINITY; m1[ct] = -INFINITY; }

  // per-lane base: row = 512*wave + chunk*16 + cl, k-octet o (both ksubs)
  const float* Fa = F + (size_t)a * VV * DD + (size_t)wave * 512 * DD
                    + cl * DD + o * 8;

#define LOADC(S0, S1, S2, S3, CH) {                                  \
    const float* _p = Fa + (size_t)(CH) * 16 * DD;                   \
    S0 = *(const float4*)(_p);      S1 = *(const float4*)(_p + 4);   \
    S2 = *(const float4*)(_p + 32); S3 = *(const float4*)(_p + 36); }

#define STAGE(S0, S1, S2, S3, CH, REFILL) {                          \
    f16x8 a0, a1;                                                    \
    a0[0] = (_Float16)S0.x; a0[1] = (_Float16)S0.y;                  \
    a0[2] = (_Float16)S0.z; a0[3] = (_Float16)S0.w;                  \
    a0[4] = (_Float16)S1.x; a0[5] = (_Float16)S1.y;                  \
    a0[6] = (_Float16)S1.z; a0[7] = (_Float16)S1.w;                  \
    a1[0] = (_Float16)S2.x; a1[1] = (_Float16)S2.y;                  \
    a1[2] = (_Float16)S2.z; a1[3] = (_Float16)S2.w;                  \
    a1[4] = (_Float16)S3.x; a1[5] = (_Float16)S3.y;                  \
    a1[6] = (_Float16)S3.z; a1[7] = (_Float16)S3.w;                  \
    if (REFILL) LOADC(S0, S1, S2, S3, (CH) + 3)                      \
    _Pragma("unroll")                                                \
    for (int ct = 0; ct < 16; ++ct) {                                \
      f32x4 acc = {0.f, 0.f, 0.f, 0.f};                              \
      acc = __builtin_amdgcn_mfma_f32_16x16x32_f16(a0, bf[ct][0], acc, 0, 0, 0); \
      acc = __builtin_amdgcn_mfma_f32_16x16x32_f16(a1, bf[ct][1], acc, 0, 0, 0); \
      float h1 = fmaxf(acc[0], acc[1]), q1 = fminf(acc[0], acc[1]);  \
      float h2 = fmaxf(acc[2], acc[3]), q2 = fminf(acc[2], acc[3]);  \
      float M0 = fmaxf(h1, h2);                                      \
      float M1 = fmaxf(fminf(h1, h2), fmaxf(q1, q2));                \
      float old0 = m0[ct];                                           \
      m0[ct] = fmaxf(old0, M0);                                      \
      m1[ct] = fmaxf(m1[ct], fmaxf(fminf(old0, M0), M1));            \
    }                                                                \
  }

  // ---- 3-deep statically-named pipeline over 32 chunks of 16 rows ----
  float4 A0, A1, A2, A3, B0, B1, B2, B3, C0, C1, C2, C3;
  LOADC(A0, A1, A2, A3, 0)
  LOADC(B0, B1, B2, B3, 1)
  LOADC(C0, C1, C2, C3, 2)

#pragma unroll 1
  for (int q = 0; q < 10; ++q) {
    const int ch = 3 * q;                       // 0,3,...,27
    STAGE(A0, A1, A2, A3, ch,     ch + 3 < 32)  // refills 3..30
    STAGE(B0, B1, B2, B3, ch + 1, ch + 4 < 32)  // refills 4..31
    STAGE(C0, C1, C2, C3, ch + 2, ch + 5 < 32)  // refills 5..29(guarded)
  }
  // epilogue: chunks 30 (A), 31 (B) already loaded by the last refills
  STAGE(A0, A1, A2, A3, 30, 0)
  STAGE(B0, B1, B2, B3, 31, 0)
#undef STAGE
#undef LOADC

  // ---- merge across the 4 k-octet row-groups within the wave ----
#pragma unroll
  for (int ct = 0; ct < 16; ++ct) {
#pragma unroll
    for (int off = 16; off <= 32; off <<= 1) {
      float p0 = __shfl_xor(m0[ct], off);
      float p1 = __shfl_xor(m1[ct], off);
      float n1 = fmaxf(fminf(m0[ct], p0), fmaxf(m1[ct], p1));
      m0[ct] = fmaxf(m0[ct], p0);
      m1[ct] = n1;
    }
    if (lane < 16) {
      mrg[wave][ct * 16 + lane][0] = m0[ct];
      mrg[wave][ct * 16 + lane][1] = m1[ct];
    }
  }
  __syncthreads();

  // ---- merge the 8 waves' partials; store ----
  if (t < BB) {
    float M0 = -INFINITY, M1 = -INFINITY;
#pragma unroll
    for (int w = 0; w < 8; ++w) {
      float a0 = mrg[w][t][0], a1 = mrg[w][t][1];
      float n1 = fmaxf(fminf(M0, a0), fmaxf(M1, a1));
      M0 = fmaxf(M0, a0);
      M1 = n1;
    }
    max0T[a * BB + t] = M0;
    max1T[a * BB + t] = M1;
  }
}

// ---------------------------------------------------------------------------
// Kernel 2: per row b, LSE over 511 logits, loss_b = LSE - diag.
// ---------------------------------------------------------------------------
__global__ __launch_bounds__(256) void lse_kernel(
    const float* __restrict__ max0T, const float* __restrict__ max1T,
    float* __restrict__ lossb)
{
  __shared__ float red[256];
  __shared__ float diag;
  const int b = blockIdx.x;
  const int t = threadIdx.x;     // t = a
  float x0 = max0T[t * BB + b];
  float x1 = (t == b) ? -INFINITY : max1T[t * BB + b];
  if (t == b) diag = x0;
  red[t] = fmaxf(x0, x1);
  __syncthreads();
  for (int s = 128; s > 0; s >>= 1) {
    if (t < s) red[t] = fmaxf(red[t], red[t + s]);
    __syncthreads();
  }
  float M = red[0];
  __syncthreads();
  float e = expf(x0 - M) + ((t == b) ? 0.0f : expf(x1 - M));
  red[t] = e;
  __syncthreads();
  for (int s = 128; s > 0; s >>= 1) {
    if (t < s) red[t] = red[t] + red[t + s];
    __syncthreads();
  }
  if (t == 0) lossb[b] = logf(red[0]) + M - diag;
}

__global__ __launch_bounds__(256) void mean_kernel(
    const float* __restrict__ lossb, float* __restrict__ out)
{
  __shared__ float red[256];
  const int t = threadIdx.x;
  red[t] = lossb[t];
  __syncthreads();
  for (int s = 128; s > 0; s >>= 1) {
    if (t < s) red[t] += red[t + s];
    __syncthreads();
  }
  if (t == 0) out[0] = red[0] * (1.0f / 256.0f);
}

extern "C" void kernel_launch(void* const* d_in, const int* in_sizes, int n_in,
                              void* d_out, int out_size, void* d_ws, size_t ws_size,
                              hipStream_t stream) {
  const float* F   = (const float*)d_in[0];   // fusion_fs [256,4096,64] fp32
  const float* lan = (const float*)d_in[1];   // lan_fs    [256,1,64]   fp32
  float* ws = (float*)d_ws;
  float* max0T = ws;                // [256*256]
  float* max1T = ws + 65536;        // [256*256]
  float* lossb = ws + 131072;       // [256]

  topk_sim_kernel<<<256, 512, 0, stream>>>(F, lan, max0T, max1T);
  lse_kernel<<<256, 256, 0, stream>>>(max0T, max1T, lossb);
  mean_kernel<<<1, 256, 0, stream>>>(lossb, (float*)d_out);
}

// Round 8
// 85.906 us; speedup vs baseline: 4.2073x; 4.2073x over previous
//
#include <hip/hip_runtime.h>
#include <math.h>

#define BB 256
#define VV 4096
#define DD 64
#define NCHUNK 32
#define CHB 32768   // chunk bytes: 128 rows x 64 d x 4 B

typedef __attribute__((ext_vector_type(8))) _Float16 f16x8;
typedef __attribute__((ext_vector_type(4))) float f32x4;
typedef __attribute__((address_space(3))) void lds_void_t;
typedef const __attribute__((address_space(1))) void gvoid_t;

// ---------------------------------------------------------------------------
// Kernel 1: one block (512 thr, 8 waves) per a.  wave = rg*4+cg:
//   rg in {0,1}: row-half of each 128-row chunk; cg in [0,4): 64-col group.
// F chunks DMA'd global->LDS once per CU (global_load_lds, wave-private 4KB
// slices, pre-swizzled SOURCE + swizzled ds_read per G21), double-buffered.
// bf[4][2] fp16 B-frags in regs (16 VGPR) -> total VGPR well under the 128
// cap this toolchain enforces for 512-thr blocks (r6/r7 lesson: deeper reg
// demand = silent spill disaster).  2-phase pipeline, one __syncthreads per
// chunk.  Output transposed: max0T[a*256+b], max1T[a*256+b].
// ---------------------------------------------------------------------------
__global__ __launch_bounds__(512) void topk_sim_kernel(
    const float* __restrict__ F, const float* __restrict__ lan,
    float* __restrict__ max0T, float* __restrict__ max1T)
{
  extern __shared__ __align__(16) char smem[];   // 2*32KB fbuf + 4KB mrg
  char* fbuf0 = smem;
  char* fbuf1 = smem + CHB;
  float* mrg  = (float*)(smem + 2 * CHB);        // [8][64][2]

  const int t = threadIdx.x;
  const int a = blockIdx.x;
  const int wave = t >> 6;
  const int lane = t & 63;
  const int cl = lane & 15;      // row (A) / col (B/C) within 16x16 tile
  const int o  = lane >> 4;      // k-octet group
  const int rg = wave >> 2;      // row half
  const int cg = wave & 3;       // col quarter

  const char* gFa = (const char*)(F + (size_t)a * VV * DD);

  // pre-swizzled per-lane global source offsets for the 4 staging instrs.
  // LDS linear slot' = cl; stored data must be global slot = cl ^ (row&7)
  // so that a read of (row, slot) at LDS (row, slot^(row&7)) is correct.
  int soff[4];
#pragma unroll
  for (int i = 0; i < 4; ++i) {
    int row = wave * 16 + i * 4 + o;             // row in [0,128)
    soff[i] = row * 256 + (cl ^ (row & 7)) * 16;
  }

  auto stage = [&](int ch, char* buf) {
    const char* g = gFa + (size_t)ch * CHB;
    char* dst = buf + wave * 4096;               // wave-uniform base
#pragma unroll
    for (int i = 0; i < 4; ++i) {
      __builtin_amdgcn_global_load_lds(
          (gvoid_t*)(g + soff[i]),
          (lds_void_t*)(dst + i * 1024), 16, 0, 0);
    }
  };

  stage(0, fbuf0);   // DMA in flight during lan prologue

  // ---- B fragments: 4 col-tiles x 2 ksubs, fp16, direct from global ----
  f16x8 bf[4][2];
#pragma unroll
  for (int ct = 0; ct < 4; ++ct)
#pragma unroll
    for (int s = 0; s < 2; ++s) {
      const float* p = lan + (cg * 64 + ct * 16 + cl) * DD + s * 32 + o * 8;
      float4 u0 = *(const float4*)p, u1 = *(const float4*)(p + 4);
      f16x8 v;
      v[0] = (_Float16)u0.x; v[1] = (_Float16)u0.y;
      v[2] = (_Float16)u0.z; v[3] = (_Float16)u0.w;
      v[4] = (_Float16)u1.x; v[5] = (_Float16)u1.y;
      v[6] = (_Float16)u1.z; v[7] = (_Float16)u1.w;
      bf[ct][s] = v;
    }

  float m0[4], m1[4];
#pragma unroll
  for (int ct = 0; ct < 4; ++ct) { m0[ct] = -INFINITY; m1[ct] = -INFINITY; }

  __syncthreads();   // chunk 0 staged (vmcnt drained by syncthreads)

  auto compute = [&](const char* buf) {
#pragma unroll
    for (int rt = 0; rt < 4; ++rt) {
      const int row = rg * 64 + rt * 16 + cl;
      const int rx = row & 7;
      const char* rp = buf + row * 256;
      float4 u00 = *(const float4*)(rp + ((((o * 2 + 0) ^ rx)) << 4));
      float4 u01 = *(const float4*)(rp + ((((o * 2 + 1) ^ rx)) << 4));
      float4 u10 = *(const float4*)(rp + ((8 + ((o * 2 + 0) ^ rx)) << 4));
      float4 u11 = *(const float4*)(rp + ((8 + ((o * 2 + 1) ^ rx)) << 4));
      f16x8 a0, a1;
      a0[0] = (_Float16)u00.x; a0[1] = (_Float16)u00.y;
      a0[2] = (_Float16)u00.z; a0[3] = (_Float16)u00.w;
      a0[4] = (_Float16)u01.x; a0[5] = (_Float16)u01.y;
      a0[6] = (_Float16)u01.z; a0[7] = (_Float16)u01.w;
      a1[0] = (_Float16)u10.x; a1[1] = (_Float16)u10.y;
      a1[2] = (_Float16)u10.z; a1[3] = (_Float16)u10.w;
      a1[4] = (_Float16)u11.x; a1[5] = (_Float16)u11.y;
      a1[6] = (_Float16)u11.z; a1[7] = (_Float16)u11.w;
#pragma unroll
      for (int ct = 0; ct < 4; ++ct) {
        f32x4 acc = {0.f, 0.f, 0.f, 0.f};
        acc = __builtin_amdgcn_mfma_f32_16x16x32_f16(a0, bf[ct][0], acc, 0, 0, 0);
        acc = __builtin_amdgcn_mfma_f32_16x16x32_f16(a1, bf[ct][1], acc, 0, 0, 0);
        float h1 = fmaxf(acc[0], acc[1]), q1 = fminf(acc[0], acc[1]);
        float h2 = fmaxf(acc[2], acc[3]), q2 = fminf(acc[2], acc[3]);
        float M0 = fmaxf(h1, h2);
        float M1 = fmaxf(fminf(h1, h2), fmaxf(q1, q2));
        float old0 = m0[ct];
        m0[ct] = fmaxf(old0, M0);
        m1[ct] = fmaxf(m1[ct], fmaxf(fminf(old0, M0), M1));
      }
    }
  };

  // ---- main loop: stage next, compute current, one barrier per chunk ----
#pragma unroll 1
  for (int ch = 0; ch < NCHUNK; ++ch) {
    char* cur = (ch & 1) ? fbuf1 : fbuf0;
    char* nxt = (ch & 1) ? fbuf0 : fbuf1;
    if (ch + 1 < NCHUNK) stage(ch + 1, nxt);
    compute(cur);
    __syncthreads();   // drains DMA (arrived during compute) + LDS reads
  }

  // ---- merge across the 4 k-octet row-groups within the wave ----
#pragma unroll
  for (int ct = 0; ct < 4; ++ct) {
#pragma unroll
    for (int off = 16; off <= 32; off <<= 1) {
      float p0 = __shfl_xor(m0[ct], off);
      float p1 = __shfl_xor(m1[ct], off);
      float n1 = fmaxf(fminf(m0[ct], p0), fmaxf(m1[ct], p1));
      m0[ct] = fmaxf(m0[ct], p0);
      m1[ct] = n1;
    }
    if (lane < 16) {
      mrg[(wave * 64 + ct * 16 + lane) * 2 + 0] = m0[ct];
      mrg[(wave * 64 + ct * 16 + lane) * 2 + 1] = m1[ct];
    }
  }
  __syncthreads();

  // ---- merge the 2 row-half waves of each col group; store ----
  if (t < BB) {
    const int cg2 = t >> 6, lc = t & 63;   // global col == t
    float a0 = mrg[(cg2 * 64 + lc) * 2 + 0];
    float a1 = mrg[(cg2 * 64 + lc) * 2 + 1];
    float b0 = mrg[((4 + cg2) * 64 + lc) * 2 + 0];
    float b1 = mrg[((4 + cg2) * 64 + lc) * 2 + 1];
    float M0 = fmaxf(a0, b0);
    float M1 = fmaxf(fminf(a0, b0), fmaxf(a1, b1));
    max0T[a * BB + t] = M0;
    max1T[a * BB + t] = M1;
  }
}

// ---------------------------------------------------------------------------
// Kernel 2: per row b, LSE over 511 logits, loss_b = LSE - diag.
// ---------------------------------------------------------------------------
__global__ __launch_bounds__(256) void lse_kernel(
    const float* __restrict__ max0T, const float* __restrict__ max1T,
    float* __restrict__ lossb)
{
  __shared__ float red[256];
  __shared__ float diag;
  const int b = blockIdx.x;
  const int t = threadIdx.x;     // t = a
  float x0 = max0T[t * BB + b];
  float x1 = (t == b) ? -INFINITY : max1T[t * BB + b];
  if (t == b) diag = x0;
  red[t] = fmaxf(x0, x1);
  __syncthreads();
  for (int s = 128; s > 0; s >>= 1) {
    if (t < s) red[t] = fmaxf(red[t], red[t + s]);
    __syncthreads();
  }
  float M = red[0];
  __syncthreads();
  float e = expf(x0 - M) + ((t == b) ? 0.0f : expf(x1 - M));
  red[t] = e;
  __syncthreads();
  for (int s = 128; s > 0; s >>= 1) {
    if (t < s) red[t] = red[t] + red[t + s];
    __syncthreads();
  }
  if (t == 0) lossb[b] = logf(red[0]) + M - diag;
}

__global__ __launch_bounds__(256) void mean_kernel(
    const float* __restrict__ lossb, float* __restrict__ out)
{
  __shared__ float red[256];
  const int t = threadIdx.x;
  red[t] = lossb[t];
  __syncthreads();
  for (int s = 128; s > 0; s >>= 1) {
    if (t < s) red[t] += red[t + s];
    __syncthreads();
  }
  if (t == 0) out[0] = red[0] * (1.0f / 256.0f);
}

extern "C" void kernel_launch(void* const* d_in, const int* in_sizes, int n_in,
                              void* d_out, int out_size, void* d_ws, size_t ws_size,
                              hipStream_t stream) {
  const float* F   = (const float*)d_in[0];   // fusion_fs [256,4096,64] fp32
  const float* lan = (const float*)d_in[1];   // lan_fs    [256,1,64]   fp32
  float* ws = (float*)d_ws;
  float* max0T = ws;                // [256*256]
  float* max1T = ws + 65536;        // [256*256]
  float* lossb = ws + 131072;       // [256]

  const int shmem = 2 * CHB + 8 * 64 * 2 * 4;   // 69632 B
  hipFuncSetAttribute((const void*)topk_sim_kernel,
                      hipFuncAttributeMaxDynamicSharedMemorySize, shmem);
  topk_sim_kernel<<<256, 512, shmem, stream>>>(F, lan, max0T, max1T);
  lse_kernel<<<256, 256, 0, stream>>>(max0T, max1T, lossb);
  mean_kernel<<<1, 256, 0, stream>>>(lossb, (float*)d_out);
}

// Round 10
// 72.007 us; speedup vs baseline: 5.0195x; 1.1930x over previous
//
#include <hip/hip_runtime.h>
#include <math.h>

#define BB 256
#define VV 4096
#define DD 64
#define NCHUNK 32
#define CHB 32768   // chunk bytes: 128 rows x 64 d x 4 B

typedef __attribute__((ext_vector_type(8))) _Float16 f16x8;
typedef __attribute__((ext_vector_type(2))) __fp16 fp16x2;   // cvt_pkrtz return type
typedef __attribute__((ext_vector_type(4))) float f32x4;
typedef __attribute__((address_space(3))) void lds_void_t;
typedef const __attribute__((address_space(1))) void gvoid_t;

// ---------------------------------------------------------------------------
// Kernel 1: one block (512 thr, 8 waves) per a.  wave = rg*4+cg.
// F chunks DMA'd global->LDS (wave-private 4KB slices, pre-swizzled source,
// swizzled ds_read), FOUR buffers + counted s_waitcnt vmcnt(8) + raw
// s_barrier per chunk (T3/T4): loads for 2 chunks stay in flight across
// barriers — no vmcnt(0) drain (r8 was 1-deep => latency-paced).
// Safety: stage(ch+2) overwrites ch-2's buffer; all waves passed compute(ch-2)
// at iter ch-1's barrier, which precedes this issue in program order.
// ---------------------------------------------------------------------------
__global__ __launch_bounds__(512) void topk_sim_kernel(
    const float* __restrict__ F, const float* __restrict__ lan,
    float* __restrict__ max0T, float* __restrict__ max1T)
{
  extern __shared__ __align__(16) char smem[];   // 4 x 32KB chunk buffers
  __shared__ float mrg[8][64][2];                // 4 KB static merge buffer

  const int t = threadIdx.x;
  const int a = blockIdx.x;
  const int wave = t >> 6;
  const int lane = t & 63;
  const int cl = lane & 15;      // row (A) / col (B/C) within 16x16 tile
  const int o  = lane >> 4;      // k-octet group
  const int rg = wave >> 2;      // row half
  const int cg = wave & 3;       // col quarter

  const char* gFa = (const char*)(F + (size_t)a * VV * DD);

  // pre-swizzled per-lane global source offsets (G21: linear LDS dest,
  // inverse-swizzled source, swizzled read).
  int soff[4];
#pragma unroll
  for (int i = 0; i < 4; ++i) {
    int row = wave * 16 + i * 4 + o;             // row in [0,128)
    soff[i] = row * 256 + (cl ^ (row & 7)) * 16;
  }

  auto stage = [&](int ch, char* buf) {
    const char* g = gFa + (size_t)ch * CHB;
    char* dst = buf + wave * 4096;               // wave-uniform base
#pragma unroll
    for (int i = 0; i < 4; ++i) {
      __builtin_amdgcn_global_load_lds(
          (gvoid_t*)(g + soff[i]),
          (lds_void_t*)(dst + i * 1024), 16, 0, 0);
    }
  };

  stage(0, smem);          // chunks 0,1 in flight during lan prologue
  stage(1, smem + CHB);

  // ---- B fragments: 4 col-tiles x 2 ksubs, fp16, direct from global ----
  f16x8 bf[4][2];
#pragma unroll
  for (int ct = 0; ct < 4; ++ct)
#pragma unroll
    for (int s = 0; s < 2; ++s) {
      const float* p = lan + (cg * 64 + ct * 16 + cl) * DD + s * 32 + o * 8;
      float4 u0 = *(const float4*)p, u1 = *(const float4*)(p + 4);
      union { f16x8 v; fp16x2 h[4]; } U;
      U.h[0] = __builtin_amdgcn_cvt_pkrtz(u0.x, u0.y);
      U.h[1] = __builtin_amdgcn_cvt_pkrtz(u0.z, u0.w);
      U.h[2] = __builtin_amdgcn_cvt_pkrtz(u1.x, u1.y);
      U.h[3] = __builtin_amdgcn_cvt_pkrtz(u1.z, u1.w);
      bf[ct][s] = U.v;
    }

  float m0[4], m1[4];
#pragma unroll
  for (int ct = 0; ct < 4; ++ct) { m0[ct] = -INFINITY; m1[ct] = -INFINITY; }

  auto compute = [&](const char* buf) {
#pragma unroll
    for (int rt = 0; rt < 4; ++rt) {
      const int row = rg * 64 + rt * 16 + cl;
      const int rx = row & 7;
      const char* rp = buf + row * 256;
      float4 u00 = *(const float4*)(rp + ((((o * 2 + 0) ^ rx)) << 4));
      float4 u01 = *(const float4*)(rp + ((((o * 2 + 1) ^ rx)) << 4));
      float4 u10 = *(const float4*)(rp + ((8 + ((o * 2 + 0) ^ rx)) << 4));
      float4 u11 = *(const float4*)(rp + ((8 + ((o * 2 + 1) ^ rx)) << 4));
      union { f16x8 v; fp16x2 h[4]; } A0, A1;
      A0.h[0] = __builtin_amdgcn_cvt_pkrtz(u00.x, u00.y);
      A0.h[1] = __builtin_amdgcn_cvt_pkrtz(u00.z, u00.w);
      A0.h[2] = __builtin_amdgcn_cvt_pkrtz(u01.x, u01.y);
      A0.h[3] = __builtin_amdgcn_cvt_pkrtz(u01.z, u01.w);
      A1.h[0] = __builtin_amdgcn_cvt_pkrtz(u10.x, u10.y);
      A1.h[1] = __builtin_amdgcn_cvt_pkrtz(u10.z, u10.w);
      A1.h[2] = __builtin_amdgcn_cvt_pkrtz(u11.x, u11.y);
      A1.h[3] = __builtin_amdgcn_cvt_pkrtz(u11.z, u11.w);
#pragma unroll
      for (int ct = 0; ct < 4; ++ct) {
        f32x4 acc = {0.f, 0.f, 0.f, 0.f};
        acc = __builtin_amdgcn_mfma_f32_16x16x32_f16(A0.v, bf[ct][0], acc, 0, 0, 0);
        acc = __builtin_amdgcn_mfma_f32_16x16x32_f16(A1.v, bf[ct][1], acc, 0, 0, 0);
        float h1 = fmaxf(acc[0], acc[1]), q1 = fminf(acc[0], acc[1]);
        float h2 = fmaxf(acc[2], acc[3]), q2 = fminf(acc[2], acc[3]);
        float M0 = fmaxf(h1, h2);
        float M1 = fmaxf(fminf(h1, h2), fmaxf(q1, q2));
        float old0 = m0[ct];
        m0[ct] = fmaxf(old0, M0);
        m1[ct] = fmaxf(m1[ct], fmaxf(fminf(old0, M0), M1));
      }
    }
  };

  // ---- main loop: 2-deep counted-vmcnt pipeline, 1 raw barrier/chunk ----
#pragma unroll 1
  for (int ch = 0; ch < NCHUNK; ++ch) {
    if (ch + 2 < NCHUNK) {
      stage(ch + 2, smem + (size_t)((ch + 2) & 3) * CHB);
      asm volatile("s_waitcnt vmcnt(8)" ::: "memory");   // my ch loads done
    } else if (ch + 1 < NCHUNK) {
      asm volatile("s_waitcnt vmcnt(4)" ::: "memory");
    } else {
      asm volatile("s_waitcnt vmcnt(0)" ::: "memory");
    }
    __builtin_amdgcn_s_barrier();            // everyone's ch loads done
    __builtin_amdgcn_sched_barrier(0);
    compute(smem + (size_t)(ch & 3) * CHB);
  }

  // ---- merge across the 4 k-octet row-groups within the wave ----
#pragma unroll
  for (int ct = 0; ct < 4; ++ct) {
#pragma unroll
    for (int off = 16; off <= 32; off <<= 1) {
      float p0 = __shfl_xor(m0[ct], off);
      float p1 = __shfl_xor(m1[ct], off);
      float n1 = fmaxf(fminf(m0[ct], p0), fmaxf(m1[ct], p1));
      m0[ct] = fmaxf(m0[ct], p0);
      m1[ct] = n1;
    }
    if (lane < 16) {
      mrg[wave][ct * 16 + lane][0] = m0[ct];
      mrg[wave][ct * 16 + lane][1] = m1[ct];
    }
  }
  __syncthreads();

  // ---- merge the 2 row-half waves of each col group; store ----
  if (t < BB) {
    const int cg2 = t >> 6, lc = t & 63;   // global col == t
    float a0 = mrg[cg2][lc][0],     a1 = mrg[cg2][lc][1];
    float b0 = mrg[4 + cg2][lc][0], b1 = mrg[4 + cg2][lc][1];
    float M0 = fmaxf(a0, b0);
    float M1 = fmaxf(fminf(a0, b0), fmaxf(a1, b1));
    max0T[a * BB + t] = M0;
    max1T[a * BB + t] = M1;
  }
}

// ---------------------------------------------------------------------------
// Kernel 2: per row b, LSE over 511 logits, loss_b = LSE - diag.
// ---------------------------------------------------------------------------
__global__ __launch_bounds__(256) void lse_kernel(
    const float* __restrict__ max0T, const float* __restrict__ max1T,
    float* __restrict__ lossb)
{
  __shared__ float red[256];
  __shared__ float diag;
  const int b = blockIdx.x;
  const int t = threadIdx.x;     // t = a
  float x0 = max0T[t * BB + b];
  float x1 = (t == b) ? -INFINITY : max1T[t * BB + b];
  if (t == b) diag = x0;
  red[t] = fmaxf(x0, x1);
  __syncthreads();
  for (int s = 128; s > 0; s >>= 1) {
    if (t < s) red[t] = fmaxf(red[t], red[t + s]);
    __syncthreads();
  }
  float M = red[0];
  __syncthreads();
  float e = expf(x0 - M) + ((t == b) ? 0.0f : expf(x1 - M));
  red[t] = e;
  __syncthreads();
  for (int s = 128; s > 0; s >>= 1) {
    if (t < s) red[t] = red[t] + red[t + s];
    __syncthreads();
  }
  if (t == 0) lossb[b] = logf(red[0]) + M - diag;
}

__global__ __launch_bounds__(256) void mean_kernel(
    const float* __restrict__ lossb, float* __restrict__ out)
{
  __shared__ float red[256];
  const int t = threadIdx.x;
  red[t] = lossb[t];
  __syncthreads();
  for (int s = 128; s > 0; s >>= 1) {
    if (t < s) red[t] += red[t + s];
    __syncthreads();
  }
  if (t == 0) out[0] = red[0] * (1.0f / 256.0f);
}

extern "C" void kernel_launch(void* const* d_in, const int* in_sizes, int n_in,
                              void* d_out, int out_size, void* d_ws, size_t ws_size,
                              hipStream_t stream) {
  const float* F   = (const float*)d_in[0];   // fusion_fs [256,4096,64] fp32
  const float* lan = (const float*)d_in[1];   // lan_fs    [256,1,64]   fp32
  float* ws = (float*)d_ws;
  float* max0T = ws;                // [256*256]
  float* max1T = ws + 65536;        // [256*256]
  float* lossb = ws + 131072;       // [256]

  const int shmem = 4 * CHB;        // 128 KB dynamic (+4 KB static mrg)
  hipFuncSetAttribute((const void*)topk_sim_kernel,
                      hipFuncAttributeMaxDynamicSharedMemorySize, shmem);
  topk_sim_kernel<<<256, 512, shmem, stream>>>(F, lan, max0T, max1T);
  lse_kernel<<<256, 256, 0, stream>>>(max0T, max1T, lossb);
  mean_kernel<<<1, 256, 0, stream>>>(lossb, (float*)d_out);
}